// Round 1
// baseline (830.386 us; speedup 1.0000x reference)
//
#include <hip/hip_runtime.h>
#include <cstdint>
#include <cstddef>

// ---- problem constants ----
#define Hd    3584
#define NHq   28
#define NKVh  4
#define Dh    128
#define GRP   7
#define Bb    4
#define Ss    1024
#define Tt    4096
#define NBLK  512
#define BSZ   16
#define QKVO  4608
#define VOFF  ((NHq + NKVh) * Dh)
#define ATTN_SCALE 0.08838834764831845f  // 1/sqrt(128)

typedef short s8v __attribute__((ext_vector_type(8)));   // 8 x bf16 (4 VGPRs)
typedef float f4v __attribute__((ext_vector_type(4)));   // 4 x f32 accum

__device__ __forceinline__ ushort bf16r(float f) {       // RNE f32->bf16
    uint32_t u = __float_as_uint(f);
    u += 0x7fff + ((u >> 16) & 1);
    return (ushort)(u >> 16);
}

__device__ __forceinline__ f4v mfma16(s8v a, s8v b, f4v c) {
    return __builtin_amdgcn_mfma_f32_16x16x32_bf16(a, b, c, 0, 0, 0);
}

// async global->LDS, 16B per lane; LDS dest = wave-uniform base + lane*16
__device__ __forceinline__ void async_cp16(ushort* lds, const ushort* g) {
    __builtin_amdgcn_global_load_lds(
        (const __attribute__((address_space(1))) uint32_t*)(uintptr_t)g,
        (__attribute__((address_space(3))) uint32_t*)(uintptr_t)lds,
        16, 0, 0);
}

// ---------------- fp32 -> bf16 convert (vectorized) ----------------
__global__ __launch_bounds__(256) void cvt_bf16(const float* __restrict__ src,
                                                ushort* __restrict__ dst, int n4) {
    int i = blockIdx.x * 256 + threadIdx.x;
    if (i >= n4) return;
    float4 f = ((const float4*)src)[i];
    ushort4 u;
    u.x = bf16r(f.x); u.y = bf16r(f.y); u.z = bf16r(f.z); u.w = bf16r(f.w);
    ((ushort4*)dst)[i] = u;
}

// ---------------- cache passthrough copy ----------------
__global__ __launch_bounds__(256) void copy_f4(const float* __restrict__ src,
                                               float* __restrict__ dst, int n4) {
    int i = blockIdx.x * 256 + threadIdx.x;
    if (i < n4) ((float4*)dst)[i] = ((const float4*)src)[i];
}

// ---------------- GEMM: C[M,N] = A[M,K] @ Bw[N,K]^T (+bias) ----------------
// 128x128 tile, BK=32, 4 waves each 64x64 (4x4 of 16x16x32 MFMA). m97 pattern.
__global__ __launch_bounds__(256, 3) void gemm_bt(
    const ushort* __restrict__ A, const ushort* __restrict__ Bw,
    const float* __restrict__ bias, float* __restrict__ C,
    int M, int N, int K, int hasBias)
{
    __shared__ ushort Asm_[128 * 32];
    __shared__ ushort Bsm_[128 * 32];
    const int tid  = threadIdx.x;
    const int wv   = tid >> 6;
    const int lane = tid & 63;
    const int quad = lane >> 4;
    const int l16  = lane & 15;
    const int m0 = blockIdx.y * 128;
    const int n0 = blockIdx.x * 128;
    const int wm = (wv >> 1) * 64;
    const int wn = (wv & 1) * 64;

    f4v zero = {0.f, 0.f, 0.f, 0.f};
    f4v acc[4][4];
    #pragma unroll
    for (int i = 0; i < 4; i++)
        #pragma unroll
        for (int j = 0; j < 4; j++) acc[i][j] = zero;

    // staging: wave wv, chunk c covers rows c*64 + wv*16 .. +16 of the tile
    const int rowS = wv * 16 + (lane >> 2);
    const int colS = (lane & 3) * 8;
    const ushort* gA = A  + (size_t)(m0 + rowS) * K + colS;
    const ushort* gB = Bw + (size_t)(n0 + rowS) * K + colS;
    ushort* lA = &Asm_[(wv * 16) * 32];
    ushort* lB = &Bsm_[(wv * 16) * 32];

    for (int kt = 0; kt < K; kt += 32) {
        async_cp16(lA,           gA + kt);
        async_cp16(lA + 64 * 32, gA + (size_t)64 * K + kt);
        async_cp16(lB,           gB + kt);
        async_cp16(lB + 64 * 32, gB + (size_t)64 * K + kt);
        __syncthreads();
        s8v af[4], bf[4];
        #pragma unroll
        for (int i = 0; i < 4; i++)
            af[i] = *(const s8v*)&Asm_[(wm + i * 16 + l16) * 32 + quad * 8];
        #pragma unroll
        for (int j = 0; j < 4; j++)
            bf[j] = *(const s8v*)&Bsm_[(wn + j * 16 + l16) * 32 + quad * 8];
        #pragma unroll
        for (int i = 0; i < 4; i++)
            #pragma unroll
            for (int j = 0; j < 4; j++)
                acc[i][j] = mfma16(af[i], bf[j], acc[i][j]);
        __syncthreads();
    }

    // epilogue: C/D layout col=lane&15, row=quad*4+reg
    #pragma unroll
    for (int i = 0; i < 4; i++) {
        const int m = m0 + wm + i * 16 + quad * 4;
        #pragma unroll
        for (int j = 0; j < 4; j++) {
            const int n = n0 + wn + j * 16 + l16;
            const float bv = hasBias ? bias[n] : 0.f;
            float* cp = C + (size_t)m * N + n;
            #pragma unroll
            for (int r = 0; r < 4; r++)
                cp[(size_t)r * N] = acc[i][j][r] + bv;
        }
    }
}

// ---------------- RoPE + bf16 Q/K + cache scatter ----------------
__global__ __launch_bounds__(128) void rope_scatter(
    const float* __restrict__ qkv, const int* __restrict__ pos,
    const int* __restrict__ slot_map,
    ushort* __restrict__ Qb, ushort* __restrict__ Kb, float* __restrict__ cacheOut)
{
    const int s = blockIdx.x;   // head-slot 0..35
    const int t = blockIdx.y;   // token
    const int d = threadIdx.x;  // 0..127
    float x = qkv[(size_t)t * QKVO + s * Dh + d];
    if (s < NHq + NKVh) {       // rope for q and k
        const int i = d & 63;
        const float invf = __expf(-0.14391156831212787f * (float)i); // 10000^(-2i/128)
        const float ang = (float)pos[t] * invf;
        float sv, cv;
        __sincosf(ang, &sv, &cv);
        const float other = qkv[(size_t)t * QKVO + s * Dh + (d ^ 64)];
        x = (d < 64) ? (x * cv - other * sv) : (x * cv + other * sv);
    }
    if (s < NHq) {
        Qb[((size_t)t * NHq + s) * Dh + d] = bf16r(x);
    } else {
        const int slot = slot_map[t];
        const int blk = slot >> 4, off = slot & 15;
        if (s < NHq + NKVh) {
            const int kvh = s - NHq;
            Kb[((size_t)t * NKVh + kvh) * Dh + d] = bf16r(x);
            cacheOut[(((size_t)blk * BSZ + off) * NKVh + kvh) * Dh + d] = x;
        } else {
            const int kvh = s - NHq - NKVh;
            cacheOut[(size_t)NBLK * BSZ * NKVh * Dh +
                     (((size_t)blk * BSZ + off) * NKVh + kvh) * Dh + d] = x;
        }
    }
}

// ---------------- V transpose: qkv fp32 -> Vt[b][kv][d][s] bf16 ----------------
__global__ __launch_bounds__(256) void vtrans(const float* __restrict__ qkv,
                                              ushort* __restrict__ Vt) {
    __shared__ ushort tile[32][33];
    const int tx = threadIdx.x;  // 0..31
    const int ty = threadIdx.y;  // 0..7
    const int s0 = blockIdx.x * 32;
    const int d0 = blockIdx.y * 32;
    const int b = blockIdx.z >> 2, kvh = blockIdx.z & 3;
    #pragma unroll
    for (int i = 0; i < 4; i++) {
        const int s = s0 + ty + i * 8;
        float f = qkv[(size_t)(b * Ss + s) * QKVO + VOFF + kvh * Dh + d0 + tx];
        tile[ty + i * 8][tx] = bf16r(f);
    }
    __syncthreads();
    #pragma unroll
    for (int i = 0; i < 4; i++) {
        const int d = d0 + ty + i * 8;
        Vt[((size_t)(b * NKVh + kvh) * Dh + d) * Ss + s0 + tx] = tile[tx][ty + i * 8];
    }
}

// ---------------- flash attention: 128 Q-rows/block, 128-col KV tiles ----------------
// LDS: Ksm (K tile, reused for P after QK reads) + Vsm (V^T tile) = 64 KB
__global__ __launch_bounds__(256, 2) void attn(
    const ushort* __restrict__ Qb, const ushort* __restrict__ Kb,
    const ushort* __restrict__ Vt, ushort* __restrict__ ctx)
{
    __shared__ ushort Ksm[128 * 128];
    __shared__ ushort Vsm[128 * 128];

    const int tid  = threadIdx.x;
    const int w    = tid >> 6;
    const int lane = tid & 63;
    const int quad = lane >> 4;
    const int l16  = lane & 15;
    const int qt = blockIdx.x;
    const int h  = blockIdx.y;
    const int b  = blockIdx.z;
    const int kv = h / GRP;
    const int t0 = b * Ss + qt * 128;

    // Q fragments (A-operand: m=lane&15, k=quad*8+j), held in regs for all K-tiles
    s8v qf[2][4];
    #pragma unroll
    for (int mt = 0; mt < 2; mt++)
        #pragma unroll
        for (int kd = 0; kd < 4; kd++)
            qf[mt][kd] = *(const s8v*)&Qb[((size_t)(t0 + w * 32 + mt * 16 + l16) * NHq + h) * Dh
                                          + kd * 32 + quad * 8];

    f4v zero = {0.f, 0.f, 0.f, 0.f};
    f4v o[2][8];
    #pragma unroll
    for (int mt = 0; mt < 2; mt++)
        #pragma unroll
        for (int dt = 0; dt < 8; dt++) o[mt][dt] = zero;
    float mstat[2][4], dstat[2][4];
    #pragma unroll
    for (int mt = 0; mt < 2; mt++)
        #pragma unroll
        for (int r = 0; r < 4; r++) { mstat[mt][r] = -1e30f; dstat[mt][r] = 0.f; }

    const int srow = lane >> 4;         // 0..3 row-within-wave-chunk for staging
    const int scol = l16 * 8;           // element col for staging
    const ushort* gK = Kb + ((size_t)(b * Ss) * NKVh + kv) * Dh + scol;      // + (kt*128+row)*512
    const ushort* gV = Vt + (size_t)(b * NKVh + kv) * Dh * Ss + scol;        // + row*Ss + kt*128

    for (int kt = 0; kt <= qt; kt++) {
        const bool diag = (kt == qt);
        // stage K rows (s-major) and V^T rows (d-major), 16 B/lane async
        #pragma unroll
        for (int j = 0; j < 8; j++) {
            const int row = j * 16 + w * 4 + srow;
            async_cp16(&Ksm[(j * 16 + w * 4) * 128],
                       gK + (size_t)(kt * 128 + row) * (NKVh * Dh));
            async_cp16(&Vsm[(j * 16 + w * 4) * 128],
                       gV + (size_t)row * Ss + kt * 128);
        }
        __syncthreads();

        // S = Q K^T  (wave w owns q rows w*32..+32)
        f4v sc[2][8];
        #pragma unroll
        for (int mt = 0; mt < 2; mt++)
            #pragma unroll
            for (int st = 0; st < 8; st++) sc[mt][st] = zero;
        const int smax = diag ? (2 * w + 1) : 7;   // skip fully-masked col tiles
        #pragma unroll
        for (int st = 0; st < 8; st++) {
            if (st > smax) continue;
            #pragma unroll
            for (int kd = 0; kd < 4; kd++) {
                s8v kf = *(const s8v*)&Ksm[(st * 16 + l16) * 128 + kd * 32 + quad * 8];
                sc[0][st] = mfma16(qf[0][kd], kf, sc[0][st]);
                sc[1][st] = mfma16(qf[1][kd], kf, sc[1][st]);
            }
        }

        // online softmax update (C-layout: row=quad*4+r, col=lane&15)
        float alpha[2][4];
        #pragma unroll
        for (int mt = 0; mt < 2; mt++) {
            #pragma unroll
            for (int r = 0; r < 4; r++) {
                const int lrow = w * 32 + mt * 16 + quad * 4 + r;
                float rowm = -1e30f;
                #pragma unroll
                for (int st = 0; st < 8; st++) {
                    float v = sc[mt][st][r] * ATTN_SCALE;
                    if (diag) {
                        const int col = st * 16 + l16;
                        if (col > lrow) v = -1e30f;
                    }
                    sc[mt][st][r] = v;
                    rowm = fmaxf(rowm, v);
                }
                #pragma unroll
                for (int x = 1; x < 16; x <<= 1)
                    rowm = fmaxf(rowm, __shfl_xor(rowm, x, 64));
                const float mo = mstat[mt][r];
                const float mn = fmaxf(mo, rowm);
                const float al = __expf(mo - mn);
                float rs = 0.f;
                #pragma unroll
                for (int st = 0; st < 8; st++) {
                    const float p = __expf(sc[mt][st][r] - mn);
                    sc[mt][st][r] = p;
                    rs += p;
                }
                #pragma unroll
                for (int x = 1; x < 16; x <<= 1)
                    rs += __shfl_xor(rs, x, 64);
                dstat[mt][r] = dstat[mt][r] * al + rs;
                mstat[mt][r] = mn;
                alpha[mt][r] = al;
            }
        }
        #pragma unroll
        for (int mt = 0; mt < 2; mt++)
            #pragma unroll
            for (int dt = 0; dt < 8; dt++)
                #pragma unroll
                for (int r = 0; r < 4; r++) o[mt][dt][r] *= alpha[mt][r];

        __syncthreads();   // all QK reads of Ksm done -> safe to overwrite with P
        #pragma unroll
        for (int mt = 0; mt < 2; mt++)
            #pragma unroll
            for (int st = 0; st < 8; st++)
                #pragma unroll
                for (int r = 0; r < 4; r++)
                    Ksm[(w * 32 + mt * 16 + quad * 4 + r) * 128 + st * 16 + l16] =
                        bf16r(sc[mt][st][r]);
        __syncthreads();

        // O += P V   (P from Ksm in A-layout, V^T from Vsm in B-layout)
        const int ksmax = diag ? w : 3;   // P cols beyond w*32+31 are all zero on diag
        s8v pf[2][4];
        #pragma unroll
        for (int mt = 0; mt < 2; mt++)
            #pragma unroll
            for (int ks = 0; ks < 4; ks++)
                if (ks <= ksmax)
                    pf[mt][ks] = *(const s8v*)&Ksm[(w * 32 + mt * 16 + l16) * 128
                                                   + ks * 32 + quad * 8];
        #pragma unroll
        for (int dt = 0; dt < 8; dt++) {
            #pragma unroll
            for (int ks = 0; ks < 4; ks++) {
                if (ks > ksmax) continue;
                s8v vf = *(const s8v*)&Vsm[(dt * 16 + l16) * 128 + ks * 32 + quad * 8];
                o[0][dt] = mfma16(pf[0][ks], vf, o[0][dt]);
                o[1][dt] = mfma16(pf[1][ks], vf, o[1][dt]);
            }
        }
        __syncthreads();   // all P/V reads done before next staging overwrites
    }

    // epilogue: normalize and write ctx (T, NH*D) bf16
    #pragma unroll
    for (int mt = 0; mt < 2; mt++)
        #pragma unroll
        for (int r = 0; r < 4; r++) {
            const float inv = 1.0f / dstat[mt][r];
            const int trow = t0 + w * 32 + mt * 16 + quad * 4 + r;
            #pragma unroll
            for (int dt = 0; dt < 8; dt++)
                ctx[(size_t)trow * Hd + h * Dh + dt * 16 + l16] =
                    bf16r(o[mt][dt][r] * inv);
        }
}

// ---------------- launch ----------------
extern "C" void kernel_launch(void* const* d_in, const int* in_sizes, int n_in,
                              void* d_out, int out_size, void* d_ws, size_t ws_size,
                              hipStream_t stream)
{
    const int*   positions = (const int*)d_in[0];
    const float* hidden    = (const float*)d_in[1];
    const float* kvc       = (const float*)d_in[2];
    const int*   slot_map  = (const int*)d_in[4];
    const float* w_qkv     = (const float*)d_in[7];
    const float* b_qkv     = (const float*)d_in[8];
    const float* w_o       = (const float*)d_in[9];

    float* out      = (float*)d_out;                 // (T, H) fp32
    float* cacheOut = out + (size_t)Tt * Hd;         // (2,NB,BS,NKV,D) fp32

    // workspace layout (bytes): 192 MiB total
    char* ws = (char*)d_ws;
    ushort* Xb    = (ushort*)(ws);                   // T*H bf16         29360128
    ushort* Wqkvb = (ushort*)(ws + 29360128);        // 4608*3584 bf16   33030144
    ushort* Wob   = (ushort*)(ws + 62390272);        // 3584*3584 bf16   25690112
    float*  qkv   = (float*) (ws + 88080384);        // T*4608 fp32      75497472
    ushort* Qb    = (ushort*)(ws + 163577856);       // T*NH*D bf16      29360128
    ushort* Kb    = (ushort*)(ws + 192937984);       // T*NKV*D bf16      4194304
    ushort* Vt    = (ushort*)(ws + 197132288);       // B*NKV*D*S bf16    4194304
    ushort* ctx   = Xb;                              // alias: Xb dead after GEMM1

    cvt_bf16<<<dim3(14336), 256, 0, stream>>>(hidden, Xb, 3670016);
    cvt_bf16<<<dim3(16128), 256, 0, stream>>>(w_qkv, Wqkvb, 4128768);
    cvt_bf16<<<dim3(12544), 256, 0, stream>>>(w_o, Wob, 3211264);
    gemm_bt<<<dim3(QKVO / 128, Tt / 128), 256, 0, stream>>>(
        Xb, Wqkvb, b_qkv, qkv, Tt, QKVO, Hd, 1);
    copy_f4<<<dim3(8192), 256, 0, stream>>>(kvc, cacheOut, 2097152);
    rope_scatter<<<dim3(36, Tt), 128, 0, stream>>>(qkv, positions, slot_map, Qb, Kb, cacheOut);
    vtrans<<<dim3(Ss / 32, Dh / 32, Bb * NKVh), dim3(32, 8), 0, stream>>>(qkv, Vt);
    attn<<<dim3(Ss / 128, NHq, Bb), 256, 0, stream>>>(Qb, Kb, Vt, ctx);
    gemm_bt<<<dim3(Hd / 128, Tt / 128), 256, 0, stream>>>(
        ctx, Wob, nullptr, out, Tt, Hd, Hd, 0);
}

// Round 2
// 737.355 us; speedup vs baseline: 1.1262x; 1.1262x over previous
//
#include <hip/hip_runtime.h>
#include <cstdint>
#include <cstddef>

// ---- problem constants ----
#define Hd    3584
#define NHq   28
#define NKVh  4
#define Dh    128
#define GRP   7
#define Bb    4
#define Ss    1024
#define Tt    4096
#define NBLK  512
#define BSZ   16
#define QKVO  4608
#define VOFF  ((NHq + NKVh) * Dh)
#define ATTN_SCALE 0.08838834764831845f  // 1/sqrt(128)

typedef short s8v __attribute__((ext_vector_type(8)));   // 8 x bf16 (4 VGPRs)
typedef float f4v __attribute__((ext_vector_type(4)));   // 4 x f32 accum

__device__ __forceinline__ ushort bf16r(float f) {       // RNE f32->bf16
    uint32_t u = __float_as_uint(f);
    u += 0x7fff + ((u >> 16) & 1);
    return (ushort)(u >> 16);
}

__device__ __forceinline__ uint32_t pkbf(float a, float b) {  // pack 2 bf16 -> b32
    return (uint32_t)bf16r(a) | ((uint32_t)bf16r(b) << 16);
}

__device__ __forceinline__ f4v mfma16(s8v a, s8v b, f4v c) {
    return __builtin_amdgcn_mfma_f32_16x16x32_bf16(a, b, c, 0, 0, 0);
}

// async global->LDS, 16B per lane; LDS dest = wave-uniform base + lane*16
__device__ __forceinline__ void async_cp16(ushort* lds, const ushort* g) {
    __builtin_amdgcn_global_load_lds(
        (const __attribute__((address_space(1))) uint32_t*)(uintptr_t)g,
        (__attribute__((address_space(3))) uint32_t*)(uintptr_t)lds,
        16, 0, 0);
}

// ---------------- fp32 -> bf16 convert (vectorized) ----------------
__global__ __launch_bounds__(256) void cvt_bf16(const float* __restrict__ src,
                                                ushort* __restrict__ dst, int n4) {
    int i = blockIdx.x * 256 + threadIdx.x;
    if (i >= n4) return;
    float4 f = ((const float4*)src)[i];
    ushort4 u;
    u.x = bf16r(f.x); u.y = bf16r(f.y); u.z = bf16r(f.z); u.w = bf16r(f.w);
    ((ushort4*)dst)[i] = u;
}

// ---------------- cache passthrough copy ----------------
__global__ __launch_bounds__(256) void copy_f4(const float* __restrict__ src,
                                               float* __restrict__ dst, int n4) {
    int i = blockIdx.x * 256 + threadIdx.x;
    if (i < n4) ((float4*)dst)[i] = ((const float4*)src)[i];
}

// ---------------- GEMM: C[M,N] = A[M,K] @ Bw[N,K]^T (+bias) ----------------
// 128x128 tile, BK=32, 4 waves each 64x64 (4x4 of 16x16x32 MFMA). m97 pattern.
// LDS row stride = 64 B (not 256) so fragment reads are already conflict-free.
__global__ __launch_bounds__(256, 3) void gemm_bt(
    const ushort* __restrict__ A, const ushort* __restrict__ Bw,
    const float* __restrict__ bias, float* __restrict__ C,
    int M, int N, int K, int hasBias)
{
    __shared__ ushort Asm_[128 * 32];
    __shared__ ushort Bsm_[128 * 32];
    const int tid  = threadIdx.x;
    const int wv   = tid >> 6;
    const int lane = tid & 63;
    const int quad = lane >> 4;
    const int l16  = lane & 15;
    const int m0 = blockIdx.y * 128;
    const int n0 = blockIdx.x * 128;
    const int wm = (wv >> 1) * 64;
    const int wn = (wv & 1) * 64;

    f4v zero = {0.f, 0.f, 0.f, 0.f};
    f4v acc[4][4];
    #pragma unroll
    for (int i = 0; i < 4; i++)
        #pragma unroll
        for (int j = 0; j < 4; j++) acc[i][j] = zero;

    const int rowS = wv * 16 + (lane >> 2);
    const int colS = (lane & 3) * 8;
    const ushort* gA = A  + (size_t)(m0 + rowS) * K + colS;
    const ushort* gB = Bw + (size_t)(n0 + rowS) * K + colS;
    ushort* lA = &Asm_[(wv * 16) * 32];
    ushort* lB = &Bsm_[(wv * 16) * 32];

    for (int kt = 0; kt < K; kt += 32) {
        async_cp16(lA,           gA + kt);
        async_cp16(lA + 64 * 32, gA + (size_t)64 * K + kt);
        async_cp16(lB,           gB + kt);
        async_cp16(lB + 64 * 32, gB + (size_t)64 * K + kt);
        __syncthreads();
        s8v af[4], bf[4];
        #pragma unroll
        for (int i = 0; i < 4; i++)
            af[i] = *(const s8v*)&Asm_[(wm + i * 16 + l16) * 32 + quad * 8];
        #pragma unroll
        for (int j = 0; j < 4; j++)
            bf[j] = *(const s8v*)&Bsm_[(wn + j * 16 + l16) * 32 + quad * 8];
        #pragma unroll
        for (int i = 0; i < 4; i++)
            #pragma unroll
            for (int j = 0; j < 4; j++)
                acc[i][j] = mfma16(af[i], bf[j], acc[i][j]);
        __syncthreads();
    }

    #pragma unroll
    for (int i = 0; i < 4; i++) {
        const int m = m0 + wm + i * 16 + quad * 4;
        #pragma unroll
        for (int j = 0; j < 4; j++) {
            const int n = n0 + wn + j * 16 + l16;
            const float bv = hasBias ? bias[n] : 0.f;
            float* cp = C + (size_t)m * N + n;
            #pragma unroll
            for (int r = 0; r < 4; r++)
                cp[(size_t)r * N] = acc[i][j][r] + bv;
        }
    }
}

// ---------------- RoPE + bf16 Q/K + cache scatter ----------------
__global__ __launch_bounds__(128) void rope_scatter(
    const float* __restrict__ qkv, const int* __restrict__ pos,
    const int* __restrict__ slot_map,
    ushort* __restrict__ Qb, ushort* __restrict__ Kb, float* __restrict__ cacheOut)
{
    const int s = blockIdx.x;   // head-slot 0..35
    const int t = blockIdx.y;   // token
    const int d = threadIdx.x;  // 0..127
    float x = qkv[(size_t)t * QKVO + s * Dh + d];
    if (s < NHq + NKVh) {       // rope for q and k
        const int i = d & 63;
        const float invf = __expf(-0.14391156831212787f * (float)i); // 10000^(-2i/128)
        const float ang = (float)pos[t] * invf;
        float sv, cv;
        __sincosf(ang, &sv, &cv);
        const float other = qkv[(size_t)t * QKVO + s * Dh + (d ^ 64)];
        x = (d < 64) ? (x * cv - other * sv) : (x * cv + other * sv);
    }
    if (s < NHq) {
        Qb[((size_t)t * NHq + s) * Dh + d] = bf16r(x);
    } else {
        const int slot = slot_map[t];
        const int blk = slot >> 4, off = slot & 15;
        if (s < NHq + NKVh) {
            const int kvh = s - NHq;
            Kb[((size_t)t * NKVh + kvh) * Dh + d] = bf16r(x);
            cacheOut[(((size_t)blk * BSZ + off) * NKVh + kvh) * Dh + d] = x;
        } else {
            const int kvh = s - NHq - NKVh;
            cacheOut[(size_t)NBLK * BSZ * NKVh * Dh +
                     (((size_t)blk * BSZ + off) * NKVh + kvh) * Dh + d] = x;
        }
    }
}

// ---------------- V transpose: qkv fp32 -> Vt[b][kv][d][s] bf16 ----------------
__global__ __launch_bounds__(256) void vtrans(const float* __restrict__ qkv,
                                              ushort* __restrict__ Vt) {
    __shared__ ushort tile[32][33];
    const int tx = threadIdx.x;  // 0..31
    const int ty = threadIdx.y;  // 0..7
    const int s0 = blockIdx.x * 32;
    const int d0 = blockIdx.y * 32;
    const int b = blockIdx.z >> 2, kvh = blockIdx.z & 3;
    #pragma unroll
    for (int i = 0; i < 4; i++) {
        const int s = s0 + ty + i * 8;
        float f = qkv[(size_t)(b * Ss + s) * QKVO + VOFF + kvh * Dh + d0 + tx];
        tile[ty + i * 8][tx] = bf16r(f);
    }
    __syncthreads();
    #pragma unroll
    for (int i = 0; i < 4; i++) {
        const int d = d0 + ty + i * 8;
        Vt[((size_t)(b * NKVh + kvh) * Dh + d) * Ss + s0 + tx] = tile[tx][ty + i * 8];
    }
}

// ---------------- flash attention, S^T formulation ----------------
// S^T = K Q^T (C-layout: row=s, col=q)  ->  softmax reduces across quads (2 shfl)
// P^T -> PV B-operand via 4 ds_bpermute per 32-deep slab (no LDS round trip)
// O^T = V^T P^T accumulated in C-layout (row=d, col=q)
// K/V staged with 16B xor-swizzle (chunk ^ row&15) -> conflict-free b128 reads
__global__ __launch_bounds__(256, 2) void attn(
    const ushort* __restrict__ Qb, const ushort* __restrict__ Kb,
    const ushort* __restrict__ Vt, ushort* __restrict__ ctx)
{
    __shared__ ushort Ksm[128 * 128];
    __shared__ ushort Vsm[128 * 128];

    const int tid  = threadIdx.x;
    const int w    = tid >> 6;
    const int lane = tid & 63;
    const int quad = lane >> 4;
    const int l16  = lane & 15;
    const int qt = (Ss / 128 - 1) - blockIdx.x;   // heavy blocks first
    const int h  = blockIdx.y;
    const int b  = blockIdx.z;
    const int kv = h / GRP;
    const int t0 = b * Ss + qt * 128;

    // Q fragments (B-operand: n=l16 -> q, k=quad*8+j), in regs for all kt
    s8v qf[2][4];
    #pragma unroll
    for (int nt = 0; nt < 2; nt++)
        #pragma unroll
        for (int kd = 0; kd < 4; kd++)
            qf[nt][kd] = *(const s8v*)&Qb[((size_t)(t0 + w * 32 + nt * 16 + l16) * NHq + h) * Dh
                                          + kd * 32 + quad * 8];

    f4v zero = {0.f, 0.f, 0.f, 0.f};
    f4v o[2][8];                        // O^T: o[nt][dt], row=d-local, col=q
    #pragma unroll
    for (int nt = 0; nt < 2; nt++)
        #pragma unroll
        for (int dt = 0; dt < 8; dt++) o[nt][dt] = zero;
    float mstat[2] = {-1e30f, -1e30f};
    float dstat[2] = {0.f, 0.f};

    // staging addresses (xor-swizzled source chunk)
    const int srow = lane >> 4;                      // 0..3
    const int gch  = (lane & 15) ^ (w * 4 + srow);   // swizzled 16B chunk
    const ushort* gK = Kb + (size_t)(b * Ss) * (NKVh * Dh) + kv * Dh + gch * 8;
    const ushort* gV = Vt + (size_t)(b * NKVh + kv) * Dh * Ss + gch * 8;

    // bpermute pull addresses (byte = srclane*4); fixed permutation maps
    const int srcq0 = ((quad & 1) << 1) | (quad >> 1);
    const int addr0 = (srcq0 * 16 + l16) * 4;
    const int addr1 = ((srcq0 ^ 1) * 16 + l16) * 4;
    const bool oddq = (quad & 1);
    const bool lowq = (quad < 2);

    for (int kt = 0; kt <= qt; kt++) {
        const bool diag = (kt == qt);

        #pragma unroll
        for (int j = 0; j < 8; j++) {
            const int row = j * 16 + w * 4 + srow;
            async_cp16(&Ksm[(j * 16 + w * 4) * 128],
                       gK + (size_t)(kt * 128 + row) * (NKVh * Dh));
            async_cp16(&Vsm[(j * 16 + w * 4) * 128],
                       gV + (size_t)row * Ss + kt * 128);
        }
        __syncthreads();

        // S^T = K Q^T : sc[st][nt], s = st*16+quad*4+r, q = w*32+nt*16+l16
        const int smax = diag ? (2 * w + 1) : 7;
        f4v sc[8][2];
        #pragma unroll
        for (int st = 0; st < 8; st++) { sc[st][0] = zero; sc[st][1] = zero; }
        #pragma unroll
        for (int st = 0; st < 8; st++) {
            if (st > smax) continue;
            #pragma unroll
            for (int kd = 0; kd < 4; kd++) {
                s8v kf = *(const s8v*)&Ksm[((st * 16 + l16) * 16 + ((kd * 4 + quad) ^ l16)) * 8];
                sc[st][0] = mfma16(kf, qf[0][kd], sc[st][0]);
                sc[st][1] = mfma16(kf, qf[1][kd], sc[st][1]);
            }
        }

        // online softmax per q-column (reduce across quads: 2 shuffles)
        float alpha[2];
        #pragma unroll
        for (int nt = 0; nt < 2; nt++) {
            const int qcol = w * 32 + nt * 16 + l16;
            float rowm = -1e30f;
            #pragma unroll
            for (int st = 0; st < 8; st++) {
                if (st > smax) continue;
                #pragma unroll
                for (int r = 0; r < 4; r++) {
                    float v = sc[st][nt][r] * ATTN_SCALE;
                    if (diag && (st * 16 + quad * 4 + r > qcol)) v = -1e30f;
                    sc[st][nt][r] = v;
                    rowm = fmaxf(rowm, v);
                }
            }
            rowm = fmaxf(rowm, __shfl_xor(rowm, 16, 64));
            rowm = fmaxf(rowm, __shfl_xor(rowm, 32, 64));
            const float mn = fmaxf(mstat[nt], rowm);
            const float al = __expf(mstat[nt] - mn);
            float rs = 0.f;
            #pragma unroll
            for (int st = 0; st < 8; st++) {
                if (st > smax) continue;
                #pragma unroll
                for (int r = 0; r < 4; r++) {
                    const float p = __expf(sc[st][nt][r] - mn);
                    sc[st][nt][r] = p;
                    rs += p;
                }
            }
            rs += __shfl_xor(rs, 16, 64);
            rs += __shfl_xor(rs, 32, 64);
            dstat[nt] = dstat[nt] * al + rs;
            mstat[nt] = mn;
            alpha[nt] = al;
            #pragma unroll
            for (int dt = 0; dt < 8; dt++)
                #pragma unroll
                for (int r = 0; r < 4; r++) o[nt][dt][r] *= al;
        }

        // P^T -> B-operand fragments via ds_bpermute (cross-quad only), then PV
        const int spmax = diag ? w : 3;
        #pragma unroll
        for (int sp = 0; sp < 4; sp++) {
            if (sp > spmax) continue;
            s8v pf[2];
            #pragma unroll
            for (int nt = 0; nt < 2; nt++) {
                const uint32_t a01 = pkbf(sc[2 * sp][nt][0],     sc[2 * sp][nt][1]);
                const uint32_t a23 = pkbf(sc[2 * sp][nt][2],     sc[2 * sp][nt][3]);
                const uint32_t b01 = pkbf(sc[2 * sp + 1][nt][0], sc[2 * sp + 1][nt][1]);
                const uint32_t b23 = pkbf(sc[2 * sp + 1][nt][2], sc[2 * sp + 1][nt][3]);
                const int r0 = __builtin_amdgcn_ds_bpermute(addr0, (int)(oddq ? b01 : a01));
                const int r1 = __builtin_amdgcn_ds_bpermute(addr1, (int)(oddq ? a01 : b01));
                const int r2 = __builtin_amdgcn_ds_bpermute(addr0, (int)(oddq ? b23 : a23));
                const int r3 = __builtin_amdgcn_ds_bpermute(addr1, (int)(oddq ? a23 : b23));
                union { int d[4]; s8v v; } u;
                u.d[0] = lowq ? r0 : r1;   // j0j1 (k=quad*8+0,1)
                u.d[1] = lowq ? r2 : r3;   // j2j3
                u.d[2] = lowq ? r1 : r0;   // j4j5
                u.d[3] = lowq ? r3 : r2;   // j6j7
                pf[nt] = u.v;
            }
            #pragma unroll
            for (int dt = 0; dt < 8; dt++) {
                s8v vf = *(const s8v*)&Vsm[((dt * 16 + l16) * 16 + ((sp * 4 + quad) ^ l16)) * 8];
                o[0][dt] = mfma16(vf, pf[0], o[0][dt]);
                o[1][dt] = mfma16(vf, pf[1], o[1][dt]);
            }
        }
        __syncthreads();   // LDS reads done before next staging overwrites
    }

    // epilogue: O^T -> ctx (T, NH*D) bf16, ushort4 stores (r contiguous in d)
    #pragma unroll
    for (int nt = 0; nt < 2; nt++) {
        const float inv = 1.0f / dstat[nt];
        const int trow = t0 + w * 32 + nt * 16 + l16;
        #pragma unroll
        for (int dt = 0; dt < 8; dt++) {
            ushort4 u;
            u.x = bf16r(o[nt][dt][0] * inv);
            u.y = bf16r(o[nt][dt][1] * inv);
            u.z = bf16r(o[nt][dt][2] * inv);
            u.w = bf16r(o[nt][dt][3] * inv);
            *(ushort4*)&ctx[(size_t)trow * Hd + h * Dh + dt * 16 + quad * 4] = u;
        }
    }
}

// ---------------- launch ----------------
extern "C" void kernel_launch(void* const* d_in, const int* in_sizes, int n_in,
                              void* d_out, int out_size, void* d_ws, size_t ws_size,
                              hipStream_t stream)
{
    const int*   positions = (const int*)d_in[0];
    const float* hidden    = (const float*)d_in[1];
    const float* kvc       = (const float*)d_in[2];
    const int*   slot_map  = (const int*)d_in[4];
    const float* w_qkv     = (const float*)d_in[7];
    const float* b_qkv     = (const float*)d_in[8];
    const float* w_o       = (const float*)d_in[9];

    float* out      = (float*)d_out;                 // (T, H) fp32
    float* cacheOut = out + (size_t)Tt * Hd;         // (2,NB,BS,NKV,D) fp32

    char* ws = (char*)d_ws;
    ushort* Xb    = (ushort*)(ws);                   // T*H bf16         29360128
    ushort* Wqkvb = (ushort*)(ws + 29360128);        // 4608*3584 bf16   33030144
    ushort* Wob   = (ushort*)(ws + 62390272);        // 3584*3584 bf16   25690112
    float*  qkv   = (float*) (ws + 88080384);        // T*4608 fp32      75497472
    ushort* Qb    = (ushort*)(ws + 163577856);       // T*NH*D bf16      29360128
    ushort* Kb    = (ushort*)(ws + 192937984);       // T*NKV*D bf16      4194304
    ushort* Vt    = (ushort*)(ws + 197132288);       // B*NKV*D*S bf16    4194304
    ushort* ctx   = Xb;                              // alias: Xb dead after GEMM1

    cvt_bf16<<<dim3(14336), 256, 0, stream>>>(hidden, Xb, 3670016);
    cvt_bf16<<<dim3(16128), 256, 0, stream>>>(w_qkv, Wqkvb, 4128768);
    cvt_bf16<<<dim3(12544), 256, 0, stream>>>(w_o, Wob, 3211264);
    gemm_bt<<<dim3(QKVO / 128, Tt / 128), 256, 0, stream>>>(
        Xb, Wqkvb, b_qkv, qkv, Tt, QKVO, Hd, 1);
    copy_f4<<<dim3(8192), 256, 0, stream>>>(kvc, cacheOut, 2097152);
    rope_scatter<<<dim3(36, Tt), 128, 0, stream>>>(qkv, positions, slot_map, Qb, Kb, cacheOut);
    vtrans<<<dim3(Ss / 32, Dh / 32, Bb * NKVh), dim3(32, 8), 0, stream>>>(qkv, Vt);
    attn<<<dim3(Ss / 128, NHq, Bb), 256, 0, stream>>>(Qb, Kb, Vt, ctx);
    gemm_bt<<<dim3(Hd / 128, Tt / 128), 256, 0, stream>>>(
        ctx, Wob, nullptr, out, Tt, Hd, Hd, 0);
}

// Round 3
// 721.441 us; speedup vs baseline: 1.1510x; 1.0221x over previous
//
#include <hip/hip_runtime.h>
#include <cstdint>
#include <cstddef>

// ---- problem constants ----
#define Hd    3584
#define NHq   28
#define NKVh  4
#define Dh    128
#define GRP   7
#define Bb    4
#define Ss    1024
#define Tt    4096
#define NBLK  512
#define BSZ   16
#define QKVO  4608
#define ATTN_SCALE 0.08838834764831845f  // 1/sqrt(128)

typedef short s8v __attribute__((ext_vector_type(8)));   // 8 x bf16 (4 VGPRs)
typedef float f4v __attribute__((ext_vector_type(4)));   // 4 x f32 accum

__device__ __forceinline__ ushort bf16r(float f) {       // RNE f32->bf16
    uint32_t u = __float_as_uint(f);
    u += 0x7fff + ((u >> 16) & 1);
    return (ushort)(u >> 16);
}

__device__ __forceinline__ uint32_t pkbf(float a, float b) {  // pack 2 bf16 -> b32
    return (uint32_t)bf16r(a) | ((uint32_t)bf16r(b) << 16);
}

__device__ __forceinline__ f4v mfma16(s8v a, s8v b, f4v c) {
    return __builtin_amdgcn_mfma_f32_16x16x32_bf16(a, b, c, 0, 0, 0);
}

// async global->LDS, 16B per lane; LDS dest = wave-uniform base + lane*16
__device__ __forceinline__ void async_cp16(ushort* lds, const ushort* g) {
    __builtin_amdgcn_global_load_lds(
        (const __attribute__((address_space(1))) uint32_t*)(uintptr_t)g,
        (__attribute__((address_space(3))) uint32_t*)(uintptr_t)lds,
        16, 0, 0);
}

// ---------------- fp32 -> bf16 convert (vectorized) ----------------
__global__ __launch_bounds__(256) void cvt_bf16(const float* __restrict__ src,
                                                ushort* __restrict__ dst, int n4) {
    int i = blockIdx.x * 256 + threadIdx.x;
    if (i >= n4) return;
    float4 f = ((const float4*)src)[i];
    ushort4 u;
    u.x = bf16r(f.x); u.y = bf16r(f.y); u.z = bf16r(f.z); u.w = bf16r(f.w);
    ((ushort4*)dst)[i] = u;
}

// ---------------- cache passthrough copy ----------------
__global__ __launch_bounds__(256) void copy_f4(const float* __restrict__ src,
                                               float* __restrict__ dst, int n4) {
    int i = blockIdx.x * 256 + threadIdx.x;
    if (i < n4) ((float4*)dst)[i] = ((const float4*)src)[i];
}

// ---------------- O-proj GEMM: C[M,N] = A[M,K] @ Bw[N,K]^T ----------------
// 128x128 tile, BK=32, 4 waves each 64x64. XCD-swizzled: xcd owns 4-m-tile
// stripe, n swept inner (A L2-resident, B reused across m_sub).
__global__ __launch_bounds__(256, 4) void gemm_bt(
    const ushort* __restrict__ A, const ushort* __restrict__ Bw,
    float* __restrict__ C, int N, int K)
{
    __shared__ ushort Asm_[128 * 32];
    __shared__ ushort Bsm_[128 * 32];
    const int tid  = threadIdx.x;
    const int wv   = tid >> 6;
    const int lane = tid & 63;
    const int quad = lane >> 4;
    const int l16  = lane & 15;
    // swizzle: grid (N/128, 32); per-XCD m-stripe of 4, n inner
    const int nT  = gridDim.x;
    const int lin = blockIdx.y * nT + blockIdx.x;
    const int xcd = lin & 7;
    const int j9  = lin >> 3;
    const int m0 = (xcd * 4 + j9 / nT) * 128;
    const int n0 = (j9 % nT) * 128;
    const int wm = (wv >> 1) * 64;
    const int wn = (wv & 1) * 64;

    f4v zero = {0.f, 0.f, 0.f, 0.f};
    f4v acc[4][4];
    #pragma unroll
    for (int i = 0; i < 4; i++)
        #pragma unroll
        for (int j = 0; j < 4; j++) acc[i][j] = zero;

    const int rowS = wv * 16 + (lane >> 2);
    const int colS = (lane & 3) * 8;
    const ushort* gA = A  + (size_t)(m0 + rowS) * K + colS;
    const ushort* gB = Bw + (size_t)(n0 + rowS) * K + colS;
    ushort* lA = &Asm_[(wv * 16) * 32];
    ushort* lB = &Bsm_[(wv * 16) * 32];

    for (int kt = 0; kt < K; kt += 32) {
        async_cp16(lA,           gA + kt);
        async_cp16(lA + 64 * 32, gA + (size_t)64 * K + kt);
        async_cp16(lB,           gB + kt);
        async_cp16(lB + 64 * 32, gB + (size_t)64 * K + kt);
        __syncthreads();
        s8v af[4], bf[4];
        #pragma unroll
        for (int i = 0; i < 4; i++)
            af[i] = *(const s8v*)&Asm_[(wm + i * 16 + l16) * 32 + quad * 8];
        #pragma unroll
        for (int j = 0; j < 4; j++)
            bf[j] = *(const s8v*)&Bsm_[(wn + j * 16 + l16) * 32 + quad * 8];
        #pragma unroll
        for (int i = 0; i < 4; i++)
            #pragma unroll
            for (int j = 0; j < 4; j++)
                acc[i][j] = mfma16(af[i], bf[j], acc[i][j]);
        __syncthreads();
    }

    #pragma unroll
    for (int i = 0; i < 4; i++) {
        const int m = m0 + wm + i * 16 + quad * 4;
        #pragma unroll
        for (int j = 0; j < 4; j++) {
            const int n = n0 + wn + j * 16 + l16;
            float* cp = C + (size_t)m * N + n;
            #pragma unroll
            for (int r = 0; r < 4; r++)
                cp[(size_t)r * N] = acc[i][j][r];
        }
    }
}

// ---------------- fused QKV GEMM + bias + RoPE + scatter ----------------
// qkv[M,4608] = X[M,3584] @ Wqkv^T + b.  N-tile == head slot (128 cols).
// Wave tile 32x128: RoPE partner d^64 lives in fragment j^4 of the SAME lane.
// Emits: Qb bf16 (t,28,128), Kb bf16 (t,4,128), Vt bf16 (b,4,128,1024),
//        cacheOut fp32 k/v at slot_map[t].
__global__ __launch_bounds__(256, 3) void gemm_qkv(
    const ushort* __restrict__ A, const ushort* __restrict__ Bw,
    const float* __restrict__ bias, const int* __restrict__ pos,
    const int* __restrict__ slot_map,
    ushort* __restrict__ Qb, ushort* __restrict__ Kb, ushort* __restrict__ Vt,
    float* __restrict__ cacheOut)
{
    __shared__ ushort Asm_[128 * 32];
    __shared__ ushort Bsm_[128 * 32];
    const int tid  = threadIdx.x;
    const int wv   = tid >> 6;
    const int lane = tid & 63;
    const int quad = lane >> 4;
    const int l16  = lane & 15;
    // swizzle: grid (36, 32); per-XCD m-stripe of 4, n inner
    const int lin = blockIdx.y * 36 + blockIdx.x;
    const int xcd = lin & 7;
    const int j9  = lin >> 3;          // 0..143
    const int s   = j9 % 36;           // head slot == n-tile
    const int m0  = (xcd * 4 + j9 / 36) * 128;
    const int n0  = s * 128;

    f4v zero = {0.f, 0.f, 0.f, 0.f};
    f4v acc[2][8];                     // 32 rows (tokens) x 128 cols (d)
    #pragma unroll
    for (int i = 0; i < 2; i++)
        #pragma unroll
        for (int j = 0; j < 8; j++) acc[i][j] = zero;

    const int rowS = wv * 16 + (lane >> 2);
    const int colS = (lane & 3) * 8;
    const ushort* gA = A  + (size_t)(m0 + rowS) * Hd + colS;
    const ushort* gB = Bw + (size_t)(n0 + rowS) * Hd + colS;
    ushort* lA = &Asm_[(wv * 16) * 32];
    ushort* lB = &Bsm_[(wv * 16) * 32];

    for (int kt = 0; kt < Hd; kt += 32) {
        async_cp16(lA,           gA + kt);
        async_cp16(lA + 64 * 32, gA + (size_t)64 * Hd + kt);
        async_cp16(lB,           gB + kt);
        async_cp16(lB + 64 * 32, gB + (size_t)64 * Hd + kt);
        __syncthreads();
        s8v af[2], bfr[8];
        #pragma unroll
        for (int i = 0; i < 2; i++)
            af[i] = *(const s8v*)&Asm_[(wv * 32 + i * 16 + l16) * 32 + quad * 8];
        #pragma unroll
        for (int j = 0; j < 8; j++)
            bfr[j] = *(const s8v*)&Bsm_[(j * 16 + l16) * 32 + quad * 8];
        #pragma unroll
        for (int i = 0; i < 2; i++)
            #pragma unroll
            for (int j = 0; j < 8; j++)
                acc[i][j] = mfma16(af[i], bfr[j], acc[i][j]);
        __syncthreads();
    }

    // ---- fused epilogue ----
    float bv[8];
    #pragma unroll
    for (int j = 0; j < 8; j++) bv[j] = bias[n0 + j * 16 + l16];

    if (s < NHq + NKVh) {              // Q or K: RoPE
        float invf[4];
        #pragma unroll
        for (int j = 0; j < 4; j++)
            invf[j] = __expf(-0.14391156831212787f * (float)(j * 16 + l16));
        #pragma unroll
        for (int i = 0; i < 2; i++) {
            #pragma unroll
            for (int r = 0; r < 4; r++) {
                const int t = m0 + wv * 32 + i * 16 + quad * 4 + r;
                const float p = (float)pos[t];
                float od[8];
                #pragma unroll
                for (int j = 0; j < 4; j++) {
                    float sv, cv;
                    __sincosf(p * invf[j], &sv, &cv);
                    const float x1 = acc[i][j][r] + bv[j];
                    const float x2 = acc[i][j + 4][r] + bv[j + 4];
                    od[j]     = x1 * cv - x2 * sv;
                    od[j + 4] = x2 * cv + x1 * sv;
                }
                if (s < NHq) {
                    #pragma unroll
                    for (int j = 0; j < 8; j++)
                        Qb[((size_t)t * NHq + s) * Dh + j * 16 + l16] = bf16r(od[j]);
                } else {
                    const int kvh = s - NHq;
                    const int slot = slot_map[t];
                    #pragma unroll
                    for (int j = 0; j < 8; j++) {
                        const int d = j * 16 + l16;
                        Kb[((size_t)t * NKVh + kvh) * Dh + d] = bf16r(od[j]);
                        cacheOut[(size_t)slot * (NKVh * Dh) + kvh * Dh + d] = od[j];
                    }
                }
            }
        }
    } else {                           // V: no RoPE; emit V^T + cache
        const int kvh = s - NHq - NKVh;
        #pragma unroll
        for (int i = 0; i < 2; i++) {
            #pragma unroll
            for (int r = 0; r < 4; r++) {
                const int t = m0 + wv * 32 + i * 16 + quad * 4 + r;
                const int slot = slot_map[t];
                const int b = t >> 10, stok = t & 1023;
                #pragma unroll
                for (int j = 0; j < 8; j++) {
                    const float x = acc[i][j][r] + bv[j];
                    const int d = j * 16 + l16;
                    Vt[((size_t)(b * NKVh + kvh) * Dh + d) * Ss + stok] = bf16r(x);
                    cacheOut[(size_t)NBLK * BSZ * NKVh * Dh +
                             (size_t)slot * (NKVh * Dh) + kvh * Dh + d] = x;
                }
            }
        }
    }
}

// ---------------- flash attention, S^T formulation ----------------
__global__ __launch_bounds__(256, 2) void attn(
    const ushort* __restrict__ Qb, const ushort* __restrict__ Kb,
    const ushort* __restrict__ Vt, ushort* __restrict__ ctx)
{
    __shared__ ushort Ksm[128 * 128];
    __shared__ ushort Vsm[128 * 128];

    const int tid  = threadIdx.x;
    const int w    = tid >> 6;
    const int lane = tid & 63;
    const int quad = lane >> 4;
    const int l16  = lane & 15;
    const int qt = (Ss / 128 - 1) - blockIdx.x;   // heavy blocks first
    const int h  = blockIdx.y;
    const int b  = blockIdx.z;
    const int kv = h / GRP;
    const int t0 = b * Ss + qt * 128;

    s8v qf[2][4];
    #pragma unroll
    for (int nt = 0; nt < 2; nt++)
        #pragma unroll
        for (int kd = 0; kd < 4; kd++)
            qf[nt][kd] = *(const s8v*)&Qb[((size_t)(t0 + w * 32 + nt * 16 + l16) * NHq + h) * Dh
                                          + kd * 32 + quad * 8];

    f4v zero = {0.f, 0.f, 0.f, 0.f};
    f4v o[2][8];
    #pragma unroll
    for (int nt = 0; nt < 2; nt++)
        #pragma unroll
        for (int dt = 0; dt < 8; dt++) o[nt][dt] = zero;
    float mstat[2] = {-1e30f, -1e30f};
    float dstat[2] = {0.f, 0.f};

    const int srow = lane >> 4;
    const int gch  = (lane & 15) ^ (w * 4 + srow);
    const ushort* gK = Kb + (size_t)(b * Ss) * (NKVh * Dh) + kv * Dh + gch * 8;
    const ushort* gV = Vt + (size_t)(b * NKVh + kv) * Dh * Ss + gch * 8;

    const int srcq0 = ((quad & 1) << 1) | (quad >> 1);
    const int addr0 = (srcq0 * 16 + l16) * 4;
    const int addr1 = ((srcq0 ^ 1) * 16 + l16) * 4;
    const bool oddq = (quad & 1);
    const bool lowq = (quad < 2);

    for (int kt = 0; kt <= qt; kt++) {
        const bool diag = (kt == qt);

        #pragma unroll
        for (int j = 0; j < 8; j++) {
            const int row = j * 16 + w * 4 + srow;
            async_cp16(&Ksm[(j * 16 + w * 4) * 128],
                       gK + (size_t)(kt * 128 + row) * (NKVh * Dh));
            async_cp16(&Vsm[(j * 16 + w * 4) * 128],
                       gV + (size_t)row * Ss + kt * 128);
        }
        __syncthreads();

        const int smax = diag ? (2 * w + 1) : 7;
        f4v sc[8][2];
        #pragma unroll
        for (int st = 0; st < 8; st++) { sc[st][0] = zero; sc[st][1] = zero; }
        #pragma unroll
        for (int st = 0; st < 8; st++) {
            if (st > smax) continue;
            #pragma unroll
            for (int kd = 0; kd < 4; kd++) {
                s8v kf = *(const s8v*)&Ksm[((st * 16 + l16) * 16 + ((kd * 4 + quad) ^ l16)) * 8];
                sc[st][0] = mfma16(kf, qf[0][kd], sc[st][0]);
                sc[st][1] = mfma16(kf, qf[1][kd], sc[st][1]);
            }
        }

        float alpha[2];
        #pragma unroll
        for (int nt = 0; nt < 2; nt++) {
            const int qcol = w * 32 + nt * 16 + l16;
            float rowm = -1e30f;
            #pragma unroll
            for (int st = 0; st < 8; st++) {
                if (st > smax) continue;
                #pragma unroll
                for (int r = 0; r < 4; r++) {
                    float v = sc[st][nt][r] * ATTN_SCALE;
                    if (diag && (st * 16 + quad * 4 + r > qcol)) v = -1e30f;
                    sc[st][nt][r] = v;
                    rowm = fmaxf(rowm, v);
                }
            }
            rowm = fmaxf(rowm, __shfl_xor(rowm, 16, 64));
            rowm = fmaxf(rowm, __shfl_xor(rowm, 32, 64));
            const float mn = fmaxf(mstat[nt], rowm);
            const float al = __expf(mstat[nt] - mn);
            float rs = 0.f;
            #pragma unroll
            for (int st = 0; st < 8; st++) {
                if (st > smax) continue;
                #pragma unroll
                for (int r = 0; r < 4; r++) {
                    const float p = __expf(sc[st][nt][r] - mn);
                    sc[st][nt][r] = p;
                    rs += p;
                }
            }
            rs += __shfl_xor(rs, 16, 64);
            rs += __shfl_xor(rs, 32, 64);
            dstat[nt] = dstat[nt] * al + rs;
            mstat[nt] = mn;
            alpha[nt] = al;
            #pragma unroll
            for (int dt = 0; dt < 8; dt++)
                #pragma unroll
                for (int r = 0; r < 4; r++) o[nt][dt][r] *= al;
        }

        const int spmax = diag ? w : 3;
        #pragma unroll
        for (int sp = 0; sp < 4; sp++) {
            if (sp > spmax) continue;
            s8v pf[2];
            #pragma unroll
            for (int nt = 0; nt < 2; nt++) {
                const uint32_t a01 = pkbf(sc[2 * sp][nt][0],     sc[2 * sp][nt][1]);
                const uint32_t a23 = pkbf(sc[2 * sp][nt][2],     sc[2 * sp][nt][3]);
                const uint32_t b01 = pkbf(sc[2 * sp + 1][nt][0], sc[2 * sp + 1][nt][1]);
                const uint32_t b23 = pkbf(sc[2 * sp + 1][nt][2], sc[2 * sp + 1][nt][3]);
                const int r0 = __builtin_amdgcn_ds_bpermute(addr0, (int)(oddq ? b01 : a01));
                const int r1 = __builtin_amdgcn_ds_bpermute(addr1, (int)(oddq ? a01 : b01));
                const int r2 = __builtin_amdgcn_ds_bpermute(addr0, (int)(oddq ? b23 : a23));
                const int r3 = __builtin_amdgcn_ds_bpermute(addr1, (int)(oddq ? a23 : b23));
                union { int d[4]; s8v v; } u;
                u.d[0] = lowq ? r0 : r1;
                u.d[1] = lowq ? r2 : r3;
                u.d[2] = lowq ? r1 : r0;
                u.d[3] = lowq ? r3 : r2;
                pf[nt] = u.v;
            }
            #pragma unroll
            for (int dt = 0; dt < 8; dt++) {
                s8v vf = *(const s8v*)&Vsm[((dt * 16 + l16) * 16 + ((sp * 4 + quad) ^ l16)) * 8];
                o[0][dt] = mfma16(vf, pf[0], o[0][dt]);
                o[1][dt] = mfma16(vf, pf[1], o[1][dt]);
            }
        }
        __syncthreads();
    }

    #pragma unroll
    for (int nt = 0; nt < 2; nt++) {
        const float inv = 1.0f / dstat[nt];
        const int trow = t0 + w * 32 + nt * 16 + l16;
        #pragma unroll
        for (int dt = 0; dt < 8; dt++) {
            ushort4 u;
            u.x = bf16r(o[nt][dt][0] * inv);
            u.y = bf16r(o[nt][dt][1] * inv);
            u.z = bf16r(o[nt][dt][2] * inv);
            u.w = bf16r(o[nt][dt][3] * inv);
            *(ushort4*)&ctx[(size_t)trow * Hd + h * Dh + dt * 16 + quad * 4] = u;
        }
    }
}

// ---------------- launch ----------------
extern "C" void kernel_launch(void* const* d_in, const int* in_sizes, int n_in,
                              void* d_out, int out_size, void* d_ws, size_t ws_size,
                              hipStream_t stream)
{
    const int*   positions = (const int*)d_in[0];
    const float* hidden    = (const float*)d_in[1];
    const float* kvc       = (const float*)d_in[2];
    const int*   slot_map  = (const int*)d_in[4];
    const float* w_qkv     = (const float*)d_in[7];
    const float* b_qkv     = (const float*)d_in[8];
    const float* w_o       = (const float*)d_in[9];

    float* out      = (float*)d_out;                 // (T, H) fp32
    float* cacheOut = out + (size_t)Tt * Hd;         // (2,NB,BS,NKV,D) fp32

    char* ws = (char*)d_ws;
    ushort* Xb    = (ushort*)(ws);                   // T*H bf16         29360128
    ushort* Wqkvb = (ushort*)(ws + 29360128);        // 4608*3584 bf16   33030144
    ushort* Wob   = (ushort*)(ws + 62390272);        // 3584*3584 bf16   25690112
    ushort* Qb    = (ushort*)(ws + 88080384);        // T*NH*D bf16      29360128
    ushort* Kb    = (ushort*)(ws + 117440512);       // T*NKV*D bf16      4194304
    ushort* Vt    = (ushort*)(ws + 121634816);       // B*NKV*D*S bf16    4194304
    ushort* ctx   = Xb;                              // alias: Xb dead after gemm_qkv

    cvt_bf16<<<dim3(14336), 256, 0, stream>>>(hidden, Xb, 3670016);
    cvt_bf16<<<dim3(16128), 256, 0, stream>>>(w_qkv, Wqkvb, 4128768);
    cvt_bf16<<<dim3(12544), 256, 0, stream>>>(w_o, Wob, 3211264);
    copy_f4<<<dim3(8192), 256, 0, stream>>>(kvc, cacheOut, 2097152);
    gemm_qkv<<<dim3(36, 32), 256, 0, stream>>>(
        Xb, Wqkvb, b_qkv, positions, slot_map, Qb, Kb, Vt, cacheOut);
    attn<<<dim3(Ss / 128, NHq, Bb), 256, 0, stream>>>(Qb, Kb, Vt, ctx);
    gemm_bt<<<dim3(Hd / 128, Tt / 128), 256, 0, stream>>>(
        ctx, Wob, out, Hd, Hd);
}

// Round 4
// 709.730 us; speedup vs baseline: 1.1700x; 1.0165x over previous
//
#include <hip/hip_runtime.h>
#include <cstdint>
#include <cstddef>

// ---- problem constants ----
#define Hd    3584
#define NHq   28
#define NKVh  4
#define Dh    128
#define GRP   7
#define Bb    4
#define Ss    1024
#define Tt    4096
#define NBLK  512
#define BSZ   16
#define QKVO  4608
#define ATTN_SCALE 0.08838834764831845f  // 1/sqrt(128)

typedef short s8v __attribute__((ext_vector_type(8)));   // 8 x bf16 (4 VGPRs)
typedef float f4v __attribute__((ext_vector_type(4)));   // 4 x f32 accum

__device__ __forceinline__ ushort bf16r(float f) {       // RNE f32->bf16
    uint32_t u = __float_as_uint(f);
    u += 0x7fff + ((u >> 16) & 1);
    return (ushort)(u >> 16);
}

__device__ __forceinline__ uint32_t pkbf(float a, float b) {  // pack 2 bf16 -> b32
    return (uint32_t)bf16r(a) | ((uint32_t)bf16r(b) << 16);
}

__device__ __forceinline__ f4v mfma16(s8v a, s8v b, f4v c) {
    return __builtin_amdgcn_mfma_f32_16x16x32_bf16(a, b, c, 0, 0, 0);
}

// async global->LDS, 16B per lane; LDS dest = wave-uniform base + lane*16
__device__ __forceinline__ void async_cp16(ushort* lds, const ushort* g) {
    __builtin_amdgcn_global_load_lds(
        (const __attribute__((address_space(1))) uint32_t*)(uintptr_t)g,
        (__attribute__((address_space(3))) uint32_t*)(uintptr_t)lds,
        16, 0, 0);
}

// ---------------- fp32 -> bf16 convert (vectorized) ----------------
__global__ __launch_bounds__(256) void cvt_bf16(const float* __restrict__ src,
                                                ushort* __restrict__ dst, int n4) {
    int i = blockIdx.x * 256 + threadIdx.x;
    if (i >= n4) return;
    float4 f = ((const float4*)src)[i];
    ushort4 u;
    u.x = bf16r(f.x); u.y = bf16r(f.y); u.z = bf16r(f.z); u.w = bf16r(f.w);
    ((ushort4*)dst)[i] = u;
}

// ---------------- cache passthrough copy ----------------
__global__ __launch_bounds__(256) void copy_f4(const float* __restrict__ src,
                                               float* __restrict__ dst, int n4) {
    int i = blockIdx.x * 256 + threadIdx.x;
    if (i < n4) ((float4*)dst)[i] = ((const float4*)src)[i];
}

// ---------------- O-proj GEMM: C[M,N] = A[M,K] @ Bw[N,K]^T ----------------
// 128x128 tile, BK=32, 4 waves each 64x64, linear n-fastest grid (XCD swizzle
// regressed: FETCH 206->348MB in r3). LDS xor-swizzle at 16B granularity:
// staging reads global chunk c^((row>>1)&3), fragments read chunk
// quad^((l16>>1)&3) -> 8 lanes tile the 128B bank period, 2-way = free.
__global__ __launch_bounds__(256, 4) void gemm_bt(
    const ushort* __restrict__ A, const ushort* __restrict__ Bw,
    float* __restrict__ C, int N, int K)
{
    __shared__ ushort Asm_[128 * 32];
    __shared__ ushort Bsm_[128 * 32];
    const int tid  = threadIdx.x;
    const int wv   = tid >> 6;
    const int lane = tid & 63;
    const int quad = lane >> 4;
    const int l16  = lane & 15;
    const int m0 = blockIdx.y * 128;
    const int n0 = blockIdx.x * 128;
    const int wm = (wv >> 1) * 64;
    const int wn = (wv & 1) * 64;

    f4v zero = {0.f, 0.f, 0.f, 0.f};
    f4v acc[4][4];
    #pragma unroll
    for (int i = 0; i < 4; i++)
        #pragma unroll
        for (int j = 0; j < 4; j++) acc[i][j] = zero;

    const int rowS = wv * 16 + (lane >> 2);
    const int colS = ((lane & 3) ^ ((lane >> 3) & 3)) * 8;   // swizzled source chunk
    const ushort* gA = A  + (size_t)(m0 + rowS) * K + colS;
    const ushort* gB = Bw + (size_t)(n0 + rowS) * K + colS;
    ushort* lA = &Asm_[(wv * 16) * 32];
    ushort* lB = &Bsm_[(wv * 16) * 32];
    const int fsw = ((l16 >> 1) & 3) * 8;                    // fragment chunk xor (ushorts)

    for (int kt = 0; kt < K; kt += 32) {
        async_cp16(lA,           gA + kt);
        async_cp16(lA + 64 * 32, gA + (size_t)64 * K + kt);
        async_cp16(lB,           gB + kt);
        async_cp16(lB + 64 * 32, gB + (size_t)64 * K + kt);
        __syncthreads();
        s8v af[4], bf[4];
        #pragma unroll
        for (int i = 0; i < 4; i++)
            af[i] = *(const s8v*)&Asm_[(wm + i * 16 + l16) * 32 + ((quad * 8) ^ fsw)];
        #pragma unroll
        for (int j = 0; j < 4; j++)
            bf[j] = *(const s8v*)&Bsm_[(wn + j * 16 + l16) * 32 + ((quad * 8) ^ fsw)];
        #pragma unroll
        for (int i = 0; i < 4; i++)
            #pragma unroll
            for (int j = 0; j < 4; j++)
                acc[i][j] = mfma16(af[i], bf[j], acc[i][j]);
        __syncthreads();
    }

    #pragma unroll
    for (int i = 0; i < 4; i++) {
        const int m = m0 + wm + i * 16 + quad * 4;
        #pragma unroll
        for (int j = 0; j < 4; j++) {
            const int n = n0 + wn + j * 16 + l16;
            float* cp = C + (size_t)m * N + n;
            #pragma unroll
            for (int r = 0; r < 4; r++)
                cp[(size_t)r * N] = acc[i][j][r];
        }
    }
}

// ---------------- fused QKV GEMM + bias + RoPE + scatter ----------------
// qkv[M,4608] = X[M,3584] @ Wqkv^T + b.  N-tile == head slot (128 cols).
// Wave tile 32x128: RoPE partner d^64 lives in fragment j^4 of the SAME lane.
__global__ __launch_bounds__(256, 4) void gemm_qkv(
    const ushort* __restrict__ A, const ushort* __restrict__ Bw,
    const float* __restrict__ bias, const int* __restrict__ pos,
    const int* __restrict__ slot_map,
    ushort* __restrict__ Qb, ushort* __restrict__ Kb, ushort* __restrict__ Vt,
    float* __restrict__ cacheOut)
{
    __shared__ ushort Asm_[128 * 32];
    __shared__ ushort Bsm_[128 * 32];
    const int tid  = threadIdx.x;
    const int wv   = tid >> 6;
    const int lane = tid & 63;
    const int quad = lane >> 4;
    const int l16  = lane & 15;
    const int s  = blockIdx.x;          // head slot == n-tile, 0..35
    const int m0 = blockIdx.y * 128;
    const int n0 = s * 128;

    f4v zero = {0.f, 0.f, 0.f, 0.f};
    f4v acc[2][8];                     // 32 rows (tokens) x 128 cols (d)
    #pragma unroll
    for (int i = 0; i < 2; i++)
        #pragma unroll
        for (int j = 0; j < 8; j++) acc[i][j] = zero;

    const int rowS = wv * 16 + (lane >> 2);
    const int colS = ((lane & 3) ^ ((lane >> 3) & 3)) * 8;
    const ushort* gA = A  + (size_t)(m0 + rowS) * Hd + colS;
    const ushort* gB = Bw + (size_t)(n0 + rowS) * Hd + colS;
    ushort* lA = &Asm_[(wv * 16) * 32];
    ushort* lB = &Bsm_[(wv * 16) * 32];
    const int fsw = ((l16 >> 1) & 3) * 8;

    for (int kt = 0; kt < Hd; kt += 32) {
        async_cp16(lA,           gA + kt);
        async_cp16(lA + 64 * 32, gA + (size_t)64 * Hd + kt);
        async_cp16(lB,           gB + kt);
        async_cp16(lB + 64 * 32, gB + (size_t)64 * Hd + kt);
        __syncthreads();
        s8v af[2], bfr[8];
        #pragma unroll
        for (int i = 0; i < 2; i++)
            af[i] = *(const s8v*)&Asm_[(wv * 32 + i * 16 + l16) * 32 + ((quad * 8) ^ fsw)];
        #pragma unroll
        for (int j = 0; j < 8; j++)
            bfr[j] = *(const s8v*)&Bsm_[(j * 16 + l16) * 32 + ((quad * 8) ^ fsw)];
        #pragma unroll
        for (int i = 0; i < 2; i++)
            #pragma unroll
            for (int j = 0; j < 8; j++)
                acc[i][j] = mfma16(af[i], bfr[j], acc[i][j]);
        __syncthreads();
    }

    // ---- fused epilogue ----
    float bv[8];
    #pragma unroll
    for (int j = 0; j < 8; j++) bv[j] = bias[n0 + j * 16 + l16];

    if (s < NHq + NKVh) {              // Q or K: RoPE
        float invf[4];
        #pragma unroll
        for (int j = 0; j < 4; j++)
            invf[j] = __expf(-0.14391156831212787f * (float)(j * 16 + l16));
        #pragma unroll
        for (int i = 0; i < 2; i++) {
            #pragma unroll
            for (int r = 0; r < 4; r++) {
                const int t = m0 + wv * 32 + i * 16 + quad * 4 + r;
                const float p = (float)pos[t];
                float od[8];
                #pragma unroll
                for (int j = 0; j < 4; j++) {
                    float sv, cv;
                    __sincosf(p * invf[j], &sv, &cv);
                    const float x1 = acc[i][j][r] + bv[j];
                    const float x2 = acc[i][j + 4][r] + bv[j + 4];
                    od[j]     = x1 * cv - x2 * sv;
                    od[j + 4] = x2 * cv + x1 * sv;
                }
                if (s < NHq) {
                    #pragma unroll
                    for (int j = 0; j < 8; j++)
                        Qb[((size_t)t * NHq + s) * Dh + j * 16 + l16] = bf16r(od[j]);
                } else {
                    const int kvh = s - NHq;
                    const int slot = slot_map[t];
                    #pragma unroll
                    for (int j = 0; j < 8; j++) {
                        const int d = j * 16 + l16;
                        Kb[((size_t)t * NKVh + kvh) * Dh + d] = bf16r(od[j]);
                        cacheOut[(size_t)slot * (NKVh * Dh) + kvh * Dh + d] = od[j];
                    }
                }
            }
        }
    } else {                           // V: no RoPE; emit V^T + cache
        const int kvh = s - NHq - NKVh;
        #pragma unroll
        for (int i = 0; i < 2; i++) {
            #pragma unroll
            for (int r = 0; r < 4; r++) {
                const int t = m0 + wv * 32 + i * 16 + quad * 4 + r;
                const int slot = slot_map[t];
                const int b = t >> 10, stok = t & 1023;
                #pragma unroll
                for (int j = 0; j < 8; j++) {
                    const float x = acc[i][j][r] + bv[j];
                    const int d = j * 16 + l16;
                    Vt[((size_t)(b * NKVh + kvh) * Dh + d) * Ss + stok] = bf16r(x);
                    cacheOut[(size_t)NBLK * BSZ * NKVh * Dh +
                             (size_t)slot * (NKVh * Dh) + kvh * Dh + d] = x;
                }
            }
        }
    }
}

// ---------------- flash attention, S^T formulation ----------------
__global__ __launch_bounds__(256, 2) void attn(
    const ushort* __restrict__ Qb, const ushort* __restrict__ Kb,
    const ushort* __restrict__ Vt, ushort* __restrict__ ctx)
{
    __shared__ ushort Ksm[128 * 128];
    __shared__ ushort Vsm[128 * 128];

    const int tid  = threadIdx.x;
    const int w    = tid >> 6;
    const int lane = tid & 63;
    const int quad = lane >> 4;
    const int l16  = lane & 15;
    const int qt = (Ss / 128 - 1) - blockIdx.x;   // heavy blocks first
    const int h  = blockIdx.y;
    const int b  = blockIdx.z;
    const int kv = h / GRP;
    const int t0 = b * Ss + qt * 128;

    s8v qf[2][4];
    #pragma unroll
    for (int nt = 0; nt < 2; nt++)
        #pragma unroll
        for (int kd = 0; kd < 4; kd++)
            qf[nt][kd] = *(const s8v*)&Qb[((size_t)(t0 + w * 32 + nt * 16 + l16) * NHq + h) * Dh
                                          + kd * 32 + quad * 8];

    f4v zero = {0.f, 0.f, 0.f, 0.f};
    f4v o[2][8];
    #pragma unroll
    for (int nt = 0; nt < 2; nt++)
        #pragma unroll
        for (int dt = 0; dt < 8; dt++) o[nt][dt] = zero;
    float mstat[2] = {-1e30f, -1e30f};
    float dstat[2] = {0.f, 0.f};

    const int srow = lane >> 4;
    const int gch  = (lane & 15) ^ (w * 4 + srow);
    const ushort* gK = Kb + (size_t)(b * Ss) * (NKVh * Dh) + kv * Dh + gch * 8;
    const ushort* gV = Vt + (size_t)(b * NKVh + kv) * Dh * Ss + gch * 8;

    const int srcq0 = ((quad & 1) << 1) | (quad >> 1);
    const int addr0 = (srcq0 * 16 + l16) * 4;
    const int addr1 = ((srcq0 ^ 1) * 16 + l16) * 4;
    const bool oddq = (quad & 1);
    const bool lowq = (quad < 2);

    for (int kt = 0; kt <= qt; kt++) {
        const bool diag = (kt == qt);

        #pragma unroll
        for (int j = 0; j < 8; j++) {
            const int row = j * 16 + w * 4 + srow;
            async_cp16(&Ksm[(j * 16 + w * 4) * 128],
                       gK + (size_t)(kt * 128 + row) * (NKVh * Dh));
            async_cp16(&Vsm[(j * 16 + w * 4) * 128],
                       gV + (size_t)row * Ss + kt * 128);
        }
        __syncthreads();

        const int smax = diag ? (2 * w + 1) : 7;
        f4v sc[8][2];
        #pragma unroll
        for (int st = 0; st < 8; st++) { sc[st][0] = zero; sc[st][1] = zero; }
        #pragma unroll
        for (int st = 0; st < 8; st++) {
            if (st > smax) continue;
            #pragma unroll
            for (int kd = 0; kd < 4; kd++) {
                s8v kf = *(const s8v*)&Ksm[((st * 16 + l16) * 16 + ((kd * 4 + quad) ^ l16)) * 8];
                sc[st][0] = mfma16(kf, qf[0][kd], sc[st][0]);
                sc[st][1] = mfma16(kf, qf[1][kd], sc[st][1]);
            }
        }

        float alpha[2];
        #pragma unroll
        for (int nt = 0; nt < 2; nt++) {
            const int qcol = w * 32 + nt * 16 + l16;
            float rowm = -1e30f;
            #pragma unroll
            for (int st = 0; st < 8; st++) {
                if (st > smax) continue;
                #pragma unroll
                for (int r = 0; r < 4; r++) {
                    float v = sc[st][nt][r] * ATTN_SCALE;
                    if (diag && (st * 16 + quad * 4 + r > qcol)) v = -1e30f;
                    sc[st][nt][r] = v;
                    rowm = fmaxf(rowm, v);
                }
            }
            rowm = fmaxf(rowm, __shfl_xor(rowm, 16, 64));
            rowm = fmaxf(rowm, __shfl_xor(rowm, 32, 64));
            const float mn = fmaxf(mstat[nt], rowm);
            const float al = __expf(mstat[nt] - mn);
            float rs = 0.f;
            #pragma unroll
            for (int st = 0; st < 8; st++) {
                if (st > smax) continue;
                #pragma unroll
                for (int r = 0; r < 4; r++) {
                    const float p = __expf(sc[st][nt][r] - mn);
                    sc[st][nt][r] = p;
                    rs += p;
                }
            }
            rs += __shfl_xor(rs, 16, 64);
            rs += __shfl_xor(rs, 32, 64);
            dstat[nt] = dstat[nt] * al + rs;
            mstat[nt] = mn;
            alpha[nt] = al;
            #pragma unroll
            for (int dt = 0; dt < 8; dt++)
                #pragma unroll
                for (int r = 0; r < 4; r++) o[nt][dt][r] *= al;
        }

        const int spmax = diag ? w : 3;
        #pragma unroll
        for (int sp = 0; sp < 4; sp++) {
            if (sp > spmax) continue;
            s8v pf[2];
            #pragma unroll
            for (int nt = 0; nt < 2; nt++) {
                const uint32_t a01 = pkbf(sc[2 * sp][nt][0],     sc[2 * sp][nt][1]);
                const uint32_t a23 = pkbf(sc[2 * sp][nt][2],     sc[2 * sp][nt][3]);
                const uint32_t b01 = pkbf(sc[2 * sp + 1][nt][0], sc[2 * sp + 1][nt][1]);
                const uint32_t b23 = pkbf(sc[2 * sp + 1][nt][2], sc[2 * sp + 1][nt][3]);
                const int r0 = __builtin_amdgcn_ds_bpermute(addr0, (int)(oddq ? b01 : a01));
                const int r1 = __builtin_amdgcn_ds_bpermute(addr1, (int)(oddq ? a01 : b01));
                const int r2 = __builtin_amdgcn_ds_bpermute(addr0, (int)(oddq ? b23 : a23));
                const int r3 = __builtin_amdgcn_ds_bpermute(addr1, (int)(oddq ? a23 : b23));
                union { int d[4]; s8v v; } u;
                u.d[0] = lowq ? r0 : r1;
                u.d[1] = lowq ? r2 : r3;
                u.d[2] = lowq ? r1 : r0;
                u.d[3] = lowq ? r3 : r2;
                pf[nt] = u.v;
            }
            #pragma unroll
            for (int dt = 0; dt < 8; dt++) {
                s8v vf = *(const s8v*)&Vsm[((dt * 16 + l16) * 16 + ((sp * 4 + quad) ^ l16)) * 8];
                o[0][dt] = mfma16(vf, pf[0], o[0][dt]);
                o[1][dt] = mfma16(vf, pf[1], o[1][dt]);
            }
        }
        __syncthreads();
    }

    #pragma unroll
    for (int nt = 0; nt < 2; nt++) {
        const float inv = 1.0f / dstat[nt];
        const int trow = t0 + w * 32 + nt * 16 + l16;
        #pragma unroll
        for (int dt = 0; dt < 8; dt++) {
            ushort4 u;
            u.x = bf16r(o[nt][dt][0] * inv);
            u.y = bf16r(o[nt][dt][1] * inv);
            u.z = bf16r(o[nt][dt][2] * inv);
            u.w = bf16r(o[nt][dt][3] * inv);
            *(ushort4*)&ctx[(size_t)trow * Hd + h * Dh + dt * 16 + quad * 4] = u;
        }
    }
}

// ---------------- launch ----------------
extern "C" void kernel_launch(void* const* d_in, const int* in_sizes, int n_in,
                              void* d_out, int out_size, void* d_ws, size_t ws_size,
                              hipStream_t stream)
{
    const int*   positions = (const int*)d_in[0];
    const float* hidden    = (const float*)d_in[1];
    const float* kvc       = (const float*)d_in[2];
    const int*   slot_map  = (const int*)d_in[4];
    const float* w_qkv     = (const float*)d_in[7];
    const float* b_qkv     = (const float*)d_in[8];
    const float* w_o       = (const float*)d_in[9];

    float* out      = (float*)d_out;                 // (T, H) fp32
    float* cacheOut = out + (size_t)Tt * Hd;         // (2,NB,BS,NKV,D) fp32

    char* ws = (char*)d_ws;
    ushort* Xb    = (ushort*)(ws);                   // T*H bf16         29360128
    ushort* Wqkvb = (ushort*)(ws + 29360128);        // 4608*3584 bf16   33030144
    ushort* Wob   = (ushort*)(ws + 62390272);        // 3584*3584 bf16   25690112
    ushort* Qb    = (ushort*)(ws + 88080384);        // T*NH*D bf16      29360128
    ushort* Kb    = (ushort*)(ws + 117440512);       // T*NKV*D bf16      4194304
    ushort* Vt    = (ushort*)(ws + 121634816);       // B*NKV*D*S bf16    4194304
    ushort* ctx   = Xb;                              // alias: Xb dead after gemm_qkv

    cvt_bf16<<<dim3(14336), 256, 0, stream>>>(hidden, Xb, 3670016);
    cvt_bf16<<<dim3(16128), 256, 0, stream>>>(w_qkv, Wqkvb, 4128768);
    cvt_bf16<<<dim3(12544), 256, 0, stream>>>(w_o, Wob, 3211264);
    copy_f4<<<dim3(8192), 256, 0, stream>>>(kvc, cacheOut, 2097152);
    gemm_qkv<<<dim3(36, 32), 256, 0, stream>>>(
        Xb, Wqkvb, b_qkv, positions, slot_map, Qb, Kb, Vt, cacheOut);
    attn<<<dim3(Ss / 128, NHq, Bb), 256, 0, stream>>>(Qb, Kb, Vt, ctx);
    gemm_bt<<<dim3(Hd / 128, Tt / 128), 256, 0, stream>>>(
        ctx, Wob, out, Hd, Hd);
}